// Round 6
// baseline (122.588 us; speedup 1.0000x reference)
//
#include <hip/hip_runtime.h>
#include <cstdint>

#define LTOK 12544
#define BATCH 2
#define CDIM 128
#define C3 384
#define RES 112
#define NROWS (BATCH * LTOK)  // 25088
#define SCALE 0.17677669529663687f  // 1/sqrt(32)

typedef __attribute__((ext_vector_type(8))) short bf16x8;
typedef __attribute__((ext_vector_type(4))) float f32x4;

__device__ inline ushort f2b(float f) {
    union { float f; unsigned u; } v; v.f = f;
    unsigned r = (v.u + 0x7FFFu + ((v.u >> 16) & 1u)) >> 16;
    return (ushort)r;
}
__device__ inline float b2f(ushort u) {
    union { float f; unsigned u; } v; v.u = ((unsigned)u) << 16; return v.f;
}
__device__ inline float gelu_f(float a) {
    return 0.5f * a * (1.0f + erff(a * 0.70710678118654752f));
}

// swizzled LDS accessors (kill bank conflicts on row-varying b128 access)
__device__ inline int ysIdx(int row, int el) { return row * 128 + (el ^ ((row & 7) << 3)); }  // ushort[32][128]
__device__ inline int hsIdx(int row, int el) { return row * 256 + (el ^ ((row & 7) << 3)); }  // ushort[32][256]
__device__ inline int xsIdx(int row, int el) { return row * 128 + (el ^ ((row & 7) << 2)); }  // float [32][128]

// map window-local token n -> (i, j); branch 0: W_sp=7, branch 1: W_sp=112
__device__ inline void nij(int n, int branch, int& i, int& j) {
    if (branch == 0) { i = n / 7; j = n - i * 7; }
    else             { i = n / 112; j = n - i * 112; }
}

// ---------------- K0: convert all weights to bf16 ----------------
__global__ __launch_bounds__(256) void k_cvt(const float* __restrict__ w0, const float* __restrict__ w1,
        const float* __restrict__ w2, const float* __restrict__ w3,
        ushort* __restrict__ o0, ushort* __restrict__ o1,
        ushort* __restrict__ o2, ushort* __restrict__ o3)
{
    int idx = blockIdx.x * 256 + threadIdx.x;  // vec4 index
    const float* src; ushort* dst; int vi;
    if      (idx < 12288) { src = w0; dst = o0; vi = idx; }
    else if (idx < 16384) { src = w1; dst = o1; vi = idx - 12288; }
    else if (idx < 32768) { src = w2; dst = o2; vi = idx - 16384; }
    else                  { src = w3; dst = o3; vi = idx - 32768; }
    float4 v = ((const float4*)src)[vi];
    ushort4 r; r.x = f2b(v.x); r.y = f2b(v.y); r.z = f2b(v.z); r.w = f2b(v.w);
    ((ushort4*)dst)[vi] = r;
}

// ---------------- K1: LN1 + QKV GEMM via MFMA (32 rows / 256-thread block) ----------------
__global__ __launch_bounds__(256, 2) void k_ln_qkv(const float* __restrict__ x,
        const float* __restrict__ g1, const float* __restrict__ b1,
        const ushort* __restrict__ wqkv_bf, ushort* __restrict__ qkv)
{
    __shared__ ushort ys[32 * 128];
    const int tid = threadIdx.x;
    const long long row0 = (long long)blockIdx.x * 32;

    {
        const int r = tid >> 3, l8 = tid & 7;
        const float* xr = x + (row0 + r) * CDIM + l8 * 16;
        float4 a[4];
        #pragma unroll
        for (int i = 0; i < 4; ++i) a[i] = ((const float4*)xr)[i];
        float s = 0.f, s2 = 0.f;
        #pragma unroll
        for (int i = 0; i < 4; ++i) {
            s  += a[i].x + a[i].y + a[i].z + a[i].w;
            s2 += a[i].x*a[i].x + a[i].y*a[i].y + a[i].z*a[i].z + a[i].w*a[i].w;
        }
        #pragma unroll
        for (int m = 4; m >= 1; m >>= 1) { s += __shfl_xor(s, m, 8); s2 += __shfl_xor(s2, m, 8); }
        const float mean = s * (1.f / 128.f);
        const float var = s2 * (1.f / 128.f) - mean * mean;
        const float rs = rsqrtf(var + 1e-5f);
        #pragma unroll
        for (int i = 0; i < 4; ++i) {
            float4 gg = *(const float4*)(g1 + l8 * 16 + i * 4);
            float4 bb = *(const float4*)(b1 + l8 * 16 + i * 4);
            ushort4 w;
            w.x = f2b((a[i].x - mean) * rs * gg.x + bb.x);
            w.y = f2b((a[i].y - mean) * rs * gg.y + bb.y);
            w.z = f2b((a[i].z - mean) * rs * gg.z + bb.z);
            w.w = f2b((a[i].w - mean) * rs * gg.w + bb.w);
            *(ushort4*)&ys[ysIdx(r, l8 * 16 + i * 4)] = w;
        }
    }
    __syncthreads();

    const int wv = tid >> 6, lane = tid & 63;
    const int c16 = lane & 15, g = lane >> 4;

    bf16x8 yb[2][4];
    #pragma unroll
    for (int mt = 0; mt < 2; ++mt)
        #pragma unroll
        for (int kc = 0; kc < 4; ++kc)
            yb[mt][kc] = *(const bf16x8*)&ys[ysIdx(mt * 16 + c16, kc * 32 + g * 8)];

    // preload ALL weight fragments (24 bf16x8 = 96 VGPR) -> deep load pipeline
    bf16x8 wr[6][4];
    #pragma unroll
    for (int t = 0; t < 6; ++t)
        #pragma unroll
        for (int kc = 0; kc < 4; ++kc)
            wr[t][kc] = *(const bf16x8*)&wqkv_bf[(wv * 96 + t * 16 + c16) * CDIM + kc * 32 + g * 8];

    #pragma unroll
    for (int t = 0; t < 6; ++t) {
        const int n0 = wv * 96 + t * 16;
        #pragma unroll
        for (int mt = 0; mt < 2; ++mt) {
            f32x4 acc = {0.f, 0.f, 0.f, 0.f};
            #pragma unroll
            for (int kc = 0; kc < 4; ++kc)
                acc = __builtin_amdgcn_mfma_f32_16x16x32_bf16(wr[t][kc], yb[mt][kc], acc, 0, 0, 0);
            ushort4 sv;
            sv.x = f2b(acc[0]); sv.y = f2b(acc[1]); sv.z = f2b(acc[2]); sv.w = f2b(acc[3]);
            *(ushort4*)&qkv[(row0 + mt * 16 + c16) * C3 + n0 + g * 4] = sv;
        }
    }
}

// ---------------- K2: windowed attention + LEPE via bf16 MFMA (unchanged) ----------------
__global__ __launch_bounds__(256) void k_attn_mfma(const ushort* __restrict__ qkv,
        const float* __restrict__ cw0, const float* __restrict__ cb0,
        const float* __restrict__ cw1, const float* __restrict__ cb1,
        ushort* __restrict__ att)
{
    __shared__ __align__(16) ushort ks[112 * 40];
    __shared__ __align__(16) ushort vt[32 * 136];
    __shared__ __align__(16) ushort pl[4][16 * 40];
    __shared__ __align__(16) float  ol[4][16 * 36];

    const int tid = threadIdx.x;
    const int wv = tid >> 6, lane = tid & 63;
    const int g = lane >> 4, c16 = lane & 15;

    const int wh = blockIdx.x;
    const int branch = wh >> 6;
    const int idx = wh & 63;
    const int win = idx >> 1, head = idx & 1;
    const int b = win >> 4, w = win & 15;
    const int rowBase = branch ? w * 7 : 0;
    const int colBase = branch ? 0 : w * 7;
    const float* cw = branch ? cw1 : cw0;
    const float* cb = branch ? cb1 : cb0;
    const int cbase = branch * 64 + head * 32;
    const long long qkvB = (long long)b * LTOK * C3;

    {
        const int row = tid >> 3, cwd = tid & 7;
        *(unsigned*)&vt[row * 136 + 112 + cwd * 2] = 0u;
    }

    const int t0 = blockIdx.y * 7 + 2 * wv;
    const int nt = (2 * wv + 1 < 7) ? 2 : 1;

    bf16x8 qf[2];
    #pragma unroll
    for (int t = 0; t < 2; ++t) if (t < nt) {
        int n = (t0 + t) * 16 + c16;
        int i, j; nij(n, branch, i, j);
        const ushort* qp = qkv + qkvB + (long long)((rowBase + i) * RES + colBase + j) * C3 + cbase + g * 8;
        bf16x8 qq = *(const bf16x8*)qp;
        #pragma unroll
        for (int e = 0; e < 8; ++e) qq[e] = (short)f2b(b2f((ushort)qq[e]) * SCALE);
        qf[t] = qq;
    }

    f32x4 O00 = {0.f,0.f,0.f,0.f}, O01 = {0.f,0.f,0.f,0.f};
    f32x4 O10 = {0.f,0.f,0.f,0.f}, O11 = {0.f,0.f,0.f,0.f};
    float lsum0[4] = {0.f,0.f,0.f,0.f};
    float lsum1[4] = {0.f,0.f,0.f,0.f};

    for (int cc = 0; cc < 7; ++cc) {
        __syncthreads();
        for (int u = tid; u < 448; u += 256) {
            const int key = u >> 2, d8 = (u & 3) * 8;
            const int n = cc * 112 + key;
            int i, j; nij(n, branch, i, j);
            const ushort* base = qkv + qkvB + (long long)((rowBase + i) * RES + colBase + j) * C3 + cbase + d8;
            bf16x8 kk = *(const bf16x8*)(base + 128);
            bf16x8 vv = *(const bf16x8*)(base + 256);
            *(bf16x8*)&ks[key * 40 + d8] = kk;
            #pragma unroll
            for (int e = 0; e < 8; ++e) vt[(d8 + e) * 136 + key] = (ushort)vv[e];
        }
        __syncthreads();

        #pragma unroll
        for (int p = 0; p < 4; ++p) {
            bf16x8 kf0 = *(const bf16x8*)&ks[(p * 32 + c16) * 40 + g * 8];
            bf16x8 kf1;
            if (p < 3) kf1 = *(const bf16x8*)&ks[(p * 32 + 16 + c16) * 40 + g * 8];
            bf16x8 vf0 = *(const bf16x8*)&vt[c16 * 136 + p * 32 + g * 8];
            bf16x8 vf1 = *(const bf16x8*)&vt[(16 + c16) * 136 + p * 32 + g * 8];
            ushort* pb = &pl[wv][0];

            #pragma unroll
            for (int t = 0; t < 2; ++t) if (t < nt) {
                const bf16x8 qq = t ? qf[1] : qf[0];
                f32x4 z = {0.f,0.f,0.f,0.f};
                f32x4 S0 = __builtin_amdgcn_mfma_f32_16x16x32_bf16(qq, kf0, z, 0, 0, 0);
                f32x4 S1 = z;
                if (p < 3) S1 = __builtin_amdgcn_mfma_f32_16x16x32_bf16(qq, kf1, z, 0, 0, 0);
                ushort pw0[4], pw1[4];
                #pragma unroll
                for (int r = 0; r < 4; ++r) {
                    float e0 = __expf(S0[r]);
                    if (t) lsum1[r] += e0; else lsum0[r] += e0;
                    pw0[r] = f2b(e0);
                    if (p < 3) {
                        float e1 = __expf(S1[r]);
                        if (t) lsum1[r] += e1; else lsum0[r] += e1;
                        pw1[r] = f2b(e1);
                    } else pw1[r] = 0;
                }
                #pragma unroll
                for (int r = 0; r < 4; ++r) {
                    pb[(g * 4 + r) * 40 + c16]      = pw0[r];
                    pb[(g * 4 + r) * 40 + 16 + c16] = pw1[r];
                }
                bf16x8 pf = *(const bf16x8*)&pb[c16 * 40 + g * 8];
                if (t) {
                    O10 = __builtin_amdgcn_mfma_f32_16x16x32_bf16(pf, vf0, O10, 0, 0, 0);
                    O11 = __builtin_amdgcn_mfma_f32_16x16x32_bf16(pf, vf1, O11, 0, 0, 0);
                } else {
                    O00 = __builtin_amdgcn_mfma_f32_16x16x32_bf16(pf, vf0, O00, 0, 0, 0);
                    O01 = __builtin_amdgcn_mfma_f32_16x16x32_bf16(pf, vf1, O01, 0, 0, 0);
                }
            }
        }
    }

    const int H_sp = branch ? 7 : RES;
    const int W_sp = branch ? RES : 7;
    #pragma unroll
    for (int t = 0; t < 2; ++t) if (t < nt) {
        float* ob = &ol[wv][0];
        #pragma unroll
        for (int r = 0; r < 4; ++r) {
            float s = t ? lsum1[r] : lsum0[r];
            s += __shfl_xor(s, 1); s += __shfl_xor(s, 2);
            s += __shfl_xor(s, 4); s += __shfl_xor(s, 8);
            const float inv = 1.f / s;
            const f32x4 Oa = t ? O10 : O00;
            const f32x4 Ob = t ? O11 : O01;
            ob[(g * 4 + r) * 36 + c16]      = Oa[r] * inv;
            ob[(g * 4 + r) * 36 + 16 + c16] = Ob[r] * inv;
        }
        const int r2 = lane >> 2, db = (lane & 3) * 8;
        const int n0 = (t0 + t) * 16 + r2;
        int i0, j0; nij(n0, branch, i0, j0);
        float acc[8];
        #pragma unroll
        for (int e = 0; e < 8; ++e) acc[e] = ob[r2 * 36 + db + e] + cb[head * 32 + db + e];
        #pragma unroll
        for (int dij = 0; dij < 9; ++dij) {
            const int di = dij / 3 - 1, dj = dij % 3 - 1;
            const int ii = i0 + di, jj = j0 + dj;
            if (ii >= 0 && ii < H_sp && jj >= 0 && jj < W_sp) {
                const ushort* vp = qkv + qkvB + (long long)((rowBase + ii) * RES + colBase + jj) * C3 + 256 + cbase + db;
                bf16x8 vv = *(const bf16x8*)vp;
                #pragma unroll
                for (int e = 0; e < 8; ++e)
                    acc[e] += cw[(head * 32 + db + e) * 9 + dij] * b2f((ushort)vv[e]);
            }
        }
        const long long Lq = (long long)(rowBase + i0) * RES + colBase + j0;
        ushort* op = att + ((long long)b * LTOK + Lq) * CDIM + cbase + db;
        bf16x8 ov;
        #pragma unroll
        for (int e = 0; e < 8; ++e) ov[e] = (short)f2b(acc[e]);
        *(bf16x8*)op = ov;
    }
}

// ---------------- K3: fused proj + residual + LN2 + FC1 + GELU + FC2 + residual ----------------
// 32 rows / 256-thread block; resid in regs; swizzled LDS; deep weight preload.
__global__ __launch_bounds__(256, 2) void k_pmlp(const ushort* __restrict__ att,
        const ushort* __restrict__ wproj_bf, const float* __restrict__ bproj,
        const float* __restrict__ x,
        const float* __restrict__ g2, const float* __restrict__ b2,
        const ushort* __restrict__ w1bf, const float* __restrict__ bfc1,
        const ushort* __restrict__ w2bf, const float* __restrict__ bfc2,
        float* __restrict__ out)
{
    __shared__ union {
        float  xs[32 * 128];   // 16 KB (proj result, dead after LN)
        ushort hs[32 * 256];   // 16 KB (FC1 half output)
    } u;
    __shared__ ushort ys[32 * 128];   // 8 KB
    const int tid = threadIdx.x;
    const int wv = tid >> 6, lane = tid & 63;
    const int c16 = lane & 15, g = lane >> 4;
    const long long row0 = (long long)blockIdx.x * 32;

    // ---- proj (att @ wproj^T) + bias + x  -> resid (regs) + xs (LDS) ----
    f32x4 resid[2][2];
    {
        bf16x8 ab[2][4];
        #pragma unroll
        for (int mt = 0; mt < 2; ++mt)
            #pragma unroll
            for (int kc = 0; kc < 4; ++kc)
                ab[mt][kc] = *(const bf16x8*)&att[(row0 + mt * 16 + c16) * CDIM + kc * 32 + g * 8];

        bf16x8 awp[2][4];
        #pragma unroll
        for (int tt = 0; tt < 2; ++tt)
            #pragma unroll
            for (int kc = 0; kc < 4; ++kc)
                awp[tt][kc] = *(const bf16x8*)&wproj_bf[(wv * 32 + tt * 16 + c16) * CDIM + kc * 32 + g * 8];

        #pragma unroll
        for (int tt = 0; tt < 2; ++tt) {
            const int col = wv * 32 + tt * 16 + g * 4;
            float4 bb = *(const float4*)&bproj[col];
            #pragma unroll
            for (int mt = 0; mt < 2; ++mt) {
                f32x4 a = {0.f, 0.f, 0.f, 0.f};
                #pragma unroll
                for (int kc = 0; kc < 4; ++kc)
                    a = __builtin_amdgcn_mfma_f32_16x16x32_bf16(awp[tt][kc], ab[mt][kc], a, 0, 0, 0);
                float4 xv = *(const float4*)&x[(row0 + mt * 16 + c16) * CDIM + col];
                f32x4 r;
                r[0] = a[0] + xv.x + bb.x;
                r[1] = a[1] + xv.y + bb.y;
                r[2] = a[2] + xv.z + bb.z;
                r[3] = a[3] + xv.w + bb.w;
                resid[tt][mt] = r;
                *(float4*)&u.xs[xsIdx(mt * 16 + c16, col)] = make_float4(r[0], r[1], r[2], r[3]);
            }
        }
    }
    __syncthreads();

    // ---- LN2 on xs -> ys (bf16, swizzled) ----
    {
        const int r = tid >> 3, l8 = tid & 7;
        float4 a[4];
        #pragma unroll
        for (int i = 0; i < 4; ++i) a[i] = *(const float4*)&u.xs[xsIdx(r, l8 * 16 + i * 4)];
        float s = 0.f, s2 = 0.f;
        #pragma unroll
        for (int i = 0; i < 4; ++i) {
            s  += a[i].x + a[i].y + a[i].z + a[i].w;
            s2 += a[i].x*a[i].x + a[i].y*a[i].y + a[i].z*a[i].z + a[i].w*a[i].w;
        }
        #pragma unroll
        for (int m = 4; m >= 1; m >>= 1) { s += __shfl_xor(s, m, 8); s2 += __shfl_xor(s2, m, 8); }
        const float mean = s * (1.f / 128.f);
        const float var = s2 * (1.f / 128.f) - mean * mean;
        const float rs = rsqrtf(var + 1e-5f);
        #pragma unroll
        for (int i = 0; i < 4; ++i) {
            float4 gg = *(const float4*)(g2 + l8 * 16 + i * 4);
            float4 bb = *(const float4*)(b2 + l8 * 16 + i * 4);
            ushort4 w;
            w.x = f2b((a[i].x - mean) * rs * gg.x + bb.x);
            w.y = f2b((a[i].y - mean) * rs * gg.y + bb.y);
            w.z = f2b((a[i].z - mean) * rs * gg.z + bb.z);
            w.w = f2b((a[i].w - mean) * rs * gg.w + bb.w);
            *(ushort4*)&ys[ysIdx(r, l8 * 16 + i * 4)] = w;
        }
    }
    __syncthreads();   // ys ready; xs fully consumed (hs may now overwrite)

    bf16x8 yb[2][4];
    #pragma unroll
    for (int mt = 0; mt < 2; ++mt)
        #pragma unroll
        for (int kc = 0; kc < 4; ++kc)
            yb[mt][kc] = *(const bf16x8*)&ys[ysIdx(mt * 16 + c16, kc * 32 + g * 8)];

    f32x4 acc2[2][2];
    #pragma unroll
    for (int tt = 0; tt < 2; ++tt)
        #pragma unroll
        for (int mt = 0; mt < 2; ++mt)
            acc2[tt][mt] = (f32x4){0.f, 0.f, 0.f, 0.f};

    #pragma unroll
    for (int half = 0; half < 2; ++half) {
        // preload ALL FC1 weight frags for this half (16 bf16x8 = 64 VGPR)
        bf16x8 w1r[4][4];
        #pragma unroll
        for (int t = 0; t < 4; ++t)
            #pragma unroll
            for (int kc = 0; kc < 4; ++kc)
                w1r[t][kc] = *(const bf16x8*)&w1bf[(half * 256 + wv * 64 + t * 16 + c16) * CDIM + kc * 32 + g * 8];

        // FC1 compute + GELU -> hs (swizzled)
        #pragma unroll
        for (int t = 0; t < 4; ++t) {
            const int n0g = half * 256 + wv * 64 + t * 16;
            float4 b1v = *(const float4*)&bfc1[n0g + g * 4];
            #pragma unroll
            for (int mt = 0; mt < 2; ++mt) {
                f32x4 a = {0.f, 0.f, 0.f, 0.f};
                #pragma unroll
                for (int kc = 0; kc < 4; ++kc)
                    a = __builtin_amdgcn_mfma_f32_16x16x32_bf16(w1r[t][kc], yb[mt][kc], a, 0, 0, 0);
                ushort4 sv;
                sv.x = f2b(gelu_f(a[0] + b1v.x));
                sv.y = f2b(gelu_f(a[1] + b1v.y));
                sv.z = f2b(gelu_f(a[2] + b1v.z));
                sv.w = f2b(gelu_f(a[3] + b1v.w));
                *(ushort4*)&u.hs[hsIdx(mt * 16 + c16, wv * 64 + t * 16 + g * 4)] = sv;
            }
        }

        // issue FC2 weight loads BEFORE the barrier (they fly during barrier/LDS)
        bf16x8 w2r[2][8];
        #pragma unroll
        for (int tt = 0; tt < 2; ++tt)
            #pragma unroll
            for (int kc = 0; kc < 8; ++kc)
                w2r[tt][kc] = *(const bf16x8*)&w2bf[(wv * 32 + tt * 16 + c16) * 512 + half * 256 + kc * 32 + g * 8];

        __syncthreads();

        // FC2 partial over this half's 256 h cols
        #pragma unroll
        for (int kc = 0; kc < 8; ++kc) {
            bf16x8 hb[2];
            #pragma unroll
            for (int mt = 0; mt < 2; ++mt)
                hb[mt] = *(const bf16x8*)&u.hs[hsIdx(mt * 16 + c16, kc * 32 + g * 8)];
            #pragma unroll
            for (int tt = 0; tt < 2; ++tt)
                #pragma unroll
                for (int mt = 0; mt < 2; ++mt)
                    acc2[tt][mt] = __builtin_amdgcn_mfma_f32_16x16x32_bf16(w2r[tt][kc], hb[mt], acc2[tt][mt], 0, 0, 0);
        }
        if (half == 0) __syncthreads();   // before FC1 overwrites hs
    }

    // ---- epilogue: out = acc2 + resid(reg) + bfc2 ----
    #pragma unroll
    for (int tt = 0; tt < 2; ++tt) {
        const int col = wv * 32 + tt * 16 + g * 4;
        float4 bb = *(const float4*)&bfc2[col];
        #pragma unroll
        for (int mt = 0; mt < 2; ++mt) {
            const long long row = row0 + mt * 16 + c16;
            float4 o;
            o.x = acc2[tt][mt][0] + resid[tt][mt][0] + bb.x;
            o.y = acc2[tt][mt][1] + resid[tt][mt][1] + bb.y;
            o.z = acc2[tt][mt][2] + resid[tt][mt][2] + bb.z;
            o.w = acc2[tt][mt][3] + resid[tt][mt][3] + bb.w;
            *(float4*)&out[row * CDIM + col] = o;
        }
    }
}

extern "C" void kernel_launch(void* const* d_in, const int* in_sizes, int n_in,
                              void* d_out, int out_size, void* d_ws, size_t ws_size,
                              hipStream_t stream) {
    const float* x     = (const float*)d_in[0];
    const float* g1    = (const float*)d_in[1];
    const float* b1    = (const float*)d_in[2];
    const float* wqkv  = (const float*)d_in[3];
    const float* cw0   = (const float*)d_in[4];
    const float* cb0   = (const float*)d_in[5];
    const float* cw1   = (const float*)d_in[6];
    const float* cb1   = (const float*)d_in[7];
    const float* wproj = (const float*)d_in[8];
    const float* bproj = (const float*)d_in[9];
    const float* g2    = (const float*)d_in[10];
    const float* b2    = (const float*)d_in[11];
    const float* wfc1  = (const float*)d_in[12];
    const float* bfc1  = (const float*)d_in[13];
    const float* wfc2  = (const float*)d_in[14];
    const float* bfc2  = (const float*)d_in[15];

    char* wsb = (char*)d_ws;
    ushort* qkv_bf   = (ushort*)wsb;                           // 19,267,584 B
    ushort* att_bf   = (ushort*)(wsb + 19267584);              //  6,422,528 B
    char*   wbase    = wsb + 19267584 + 6422528;
    ushort* wqkv_bf  = (ushort*)(wbase);                       // 98,304 B
    ushort* wproj_bf = (ushort*)(wbase + 98304);               // 32,768 B
    ushort* wfc1_bf  = (ushort*)(wbase + 98304 + 32768);       // 131,072 B
    ushort* wfc2_bf  = (ushort*)(wbase + 98304 + 32768 + 131072);

    float* out = (float*)d_out;

    k_cvt<<<192, 256, 0, stream>>>(wqkv, wproj, wfc1, wfc2, wqkv_bf, wproj_bf, wfc1_bf, wfc2_bf);
    k_ln_qkv<<<NROWS / 32, 256, 0, stream>>>(x, g1, b1, wqkv_bf, qkv_bf);
    k_attn_mfma<<<dim3(128, 7), 256, 0, stream>>>(qkv_bf, cw0, cb0, cw1, cb1, att_bf);
    k_pmlp<<<NROWS / 32, 256, 0, stream>>>(att_bf, wproj_bf, bproj, x, g2, b2,
                                           wfc1_bf, bfc1, wfc2_bf, bfc2, out);
}